// Round 1
// baseline (114.846 us; speedup 1.0000x reference)
//
#include <hip/hip_runtime.h>

#define NUM_CLASSES 80
constexpr int Bn = 8;
constexpr int Gn = 128;
constexpr int An = 131072;

// out layout: cls (B,A,80) | reg (B,A,4) | states (B,A)
constexpr size_t CLS_OFF = 0;
constexpr size_t REG_OFF = (size_t)Bn * An * NUM_CLASSES;
constexpr size_t ST_OFF  = REG_OFF + (size_t)Bn * An * 4;

__global__ __launch_bounds__(256) void targets_kernel(
    const float* __restrict__ ann,      // (B,G,5) x1,y1,x2,y2,label
    const float* __restrict__ anchors,  // (A,4)
    float* __restrict__ out)
{
#pragma clang fp contract(off)
    const int tid = threadIdx.x;
    const int b   = blockIdx.y;
    const int a0  = blockIdx.x * 256;
    const int a   = a0 + tid;

    // stage boxes: x1,y1,x2,y2,area,label  (8-float aligned rows)
    __shared__ float sb[Gn][8];
    for (int i = tid; i < Gn; i += 256) {
        const float* p = ann + ((size_t)b * Gn + i) * 5;
        float x1 = p[0], y1 = p[1], x2 = p[2], y2 = p[3], lab = p[4];
        sb[i][0] = x1; sb[i][1] = y1; sb[i][2] = x2; sb[i][3] = y2;
        sb[i][4] = (x2 - x1) * (y2 - y1);   // area_b, same op order as ref
        sb[i][5] = lab;
        sb[i][6] = 0.f; sb[i][7] = 0.f;
    }
    __syncthreads();

    const float4 av = *reinterpret_cast<const float4*>(anchors + (size_t)a * 4);
    const float ax1 = av.x, ay1 = av.y, ax2 = av.z, ay2 = av.w;
    const float wa = ax2 - ax1;
    const float ha = ay2 - ay1;
    const float area_a = wa * ha;   // identical to (ax2-ax1)*(ay2-ay1)

    float best = -1.0f;   // all IoUs >= 0, so g=0 always wins first
    int besti = 0;
    for (int g = 0; g < Gn; ++g) {
        const float bx1 = sb[g][0], by1 = sb[g][1];
        const float bx2 = sb[g][2], by2 = sb[g][3];
        const float area_b = sb[g][4];
        float iw = fminf(ax2, bx2) - fmaxf(ax1, bx1);
        iw = fmaxf(iw, 0.0f);
        float ih = fminf(ay2, by2) - fmaxf(ay1, by1);
        ih = fmaxf(ih, 0.0f);
        const float inter = iw * ih;
        float uni = (area_a + area_b) - inter;   // ref: area_a + area_b - inter
        uni = fmaxf(uni, 1e-8f);
        const float iou = inter / uni;           // correctly-rounded fp32 div
        if (iou > best) { best = iou; besti = g; }   // strict >: first-index ties
    }

    // states
    const float state = (best >= 0.5f) ? 1.0f : ((best < 0.4f) ? 0.0f : -1.0f);
    out[ST_OFF + (size_t)b * An + a] = state;

    // reg targets (for ALL anchors, per reference)
    const float gx1 = sb[besti][0], gy1 = sb[besti][1];
    const float gx2 = sb[besti][2], gy2 = sb[besti][3];
    float t0 = (gx1 - ax1) / wa;
    float t1 = (gy1 - ay1) / ha;
    float t2 = (gx2 - ax2) / wa;
    float t3 = (gy2 - ay2) / ha;
    t0 = (t0 - 0.0f) / 0.2f;
    t1 = (t1 - 0.0f) / 0.2f;
    t2 = (t2 - 0.0f) / 0.2f;
    t3 = (t3 - 0.0f) / 0.2f;
    float4 rv; rv.x = t0; rv.y = t1; rv.z = t2; rv.w = t3;
    *reinterpret_cast<float4*>(out + REG_OFF + ((size_t)b * An + a) * 4) = rv;

    // cls one-hot: stage per-anchor label (or -1 if not positive), then
    // block-cooperative fully-coalesced float4 writes of the 256*80 region.
    __shared__ int slab[256];
    slab[tid] = (state == 1.0f) ? (int)sb[besti][5] : -1;
    __syncthreads();

    float4* dst = reinterpret_cast<float4*>(out + CLS_OFF + ((size_t)b * An + a0) * NUM_CLASSES);
    #pragma unroll
    for (int i = 0; i < 20; ++i) {
        const int p4  = tid + i * 256;      // 0..5119 float4s
        const int anc = p4 / 20;            // 20 float4 per anchor
        const int c0  = (p4 - anc * 20) * 4;
        const int lab = slab[anc];
        float4 v;
        v.x = (c0     == lab) ? 1.0f : 0.0f;
        v.y = (c0 + 1 == lab) ? 1.0f : 0.0f;
        v.z = (c0 + 2 == lab) ? 1.0f : 0.0f;
        v.w = (c0 + 3 == lab) ? 1.0f : 0.0f;
        dst[p4] = v;
    }
}

extern "C" void kernel_launch(void* const* d_in, const int* in_sizes, int n_in,
                              void* d_out, int out_size, void* d_ws, size_t ws_size,
                              hipStream_t stream) {
    const float* ann     = (const float*)d_in[0];   // (8,128,5)
    const float* anchors = (const float*)d_in[1];   // (131072,4)
    float* out = (float*)d_out;

    dim3 grid(An / 256, Bn, 1);
    dim3 block(256, 1, 1);
    targets_kernel<<<grid, block, 0, stream>>>(ann, anchors, out);
}

// Round 2
// 108.762 us; speedup vs baseline: 1.0559x; 1.0559x over previous
//
#include <hip/hip_runtime.h>

#define NUM_CLASSES 80
constexpr int Bn = 8;
constexpr int Gn = 128;
constexpr int An = 131072;

constexpr int TB  = 256;   // threads per block
constexpr int APT = 2;     // anchors per thread
constexpr int ABLK = TB * APT;  // 512 anchors per block

// out layout: cls (B,A,80) | reg (B,A,4) | states (B,A)
constexpr size_t CLS_OFF = 0;
constexpr size_t REG_OFF = (size_t)Bn * An * NUM_CLASSES;
constexpr size_t ST_OFF  = REG_OFF + (size_t)Bn * An * 4;

__global__ __launch_bounds__(TB, 8) void targets_kernel(
    const float* __restrict__ ann,      // (B,G,5) x1,y1,x2,y2,label
    const float* __restrict__ anchors,  // (A,4)
    float* __restrict__ out)
{
#pragma clang fp contract(off)
    const int tid = threadIdx.x;
    const int b   = blockIdx.y;
    const int a0  = blockIdx.x * ABLK;

    // stage boxes: one float4 per box (coords); labels separate
    __shared__ float4 sbox[Gn];
    __shared__ float  slabel[Gn];
    for (int i = tid; i < Gn; i += TB) {
        const float* p = ann + ((size_t)b * Gn + i) * 5;
        sbox[i] = make_float4(p[0], p[1], p[2], p[3]);
        slabel[i] = p[4];
    }
    __syncthreads();

    const int a = a0 + tid * APT;

    float ax1[APT], ay1[APT], ax2[APT], ay2[APT];
    float wa[APT], ha[APT], area_a[APT];
    float best[APT];
    int   besti[APT];
    #pragma unroll
    for (int j = 0; j < APT; ++j) {
        const float4 v = *reinterpret_cast<const float4*>(anchors + (size_t)(a + j) * 4);
        ax1[j] = v.x; ay1[j] = v.y; ax2[j] = v.z; ay2[j] = v.w;
        wa[j] = v.z - v.x;
        ha[j] = v.w - v.y;
        area_a[j] = wa[j] * ha[j];      // == (ax2-ax1)*(ay2-ay1), ref op order
        best[j] = -1.0f;                // IoU >= 0, so g=0 always wins first
        besti[j] = 0;
    }

    #pragma unroll 4
    for (int g = 0; g < Gn; ++g) {
        const float4 bv = sbox[g];       // one ds_read_b128, broadcast
        const float area_b = (bv.z - bv.x) * (bv.w - bv.y);  // ref op order
        #pragma unroll
        for (int j = 0; j < APT; ++j) {
            float iw = fminf(ax2[j], bv.z) - fmaxf(ax1[j], bv.x);
            iw = fmaxf(iw, 0.0f);
            float ih = fminf(ay2[j], bv.w) - fmaxf(ay1[j], bv.y);
            ih = fmaxf(ih, 0.0f);
            const float inter = iw * ih;
            float uni = (area_a[j] + area_b) - inter;   // ref: a + b - inter
            uni = fmaxf(uni, 1e-8f);
            const float iou = inter / uni;              // correctly-rounded div
            if (iou > best[j]) { best[j] = iou; besti[j] = g; }  // first-index ties
        }
    }

    // states (float2 store: this thread's 2 anchors are adjacent)
    float st[APT];
    #pragma unroll
    for (int j = 0; j < APT; ++j)
        st[j] = (best[j] >= 0.5f) ? 1.0f : ((best[j] < 0.4f) ? 0.0f : -1.0f);
    *reinterpret_cast<float2*>(out + ST_OFF + (size_t)b * An + a) = make_float2(st[0], st[1]);

    // reg targets
    #pragma unroll
    for (int j = 0; j < APT; ++j) {
        const float4 gt = sbox[besti[j]];
        float4 rv;
        rv.x = ((gt.x - ax1[j]) / wa[j]) / 0.2f;
        rv.y = ((gt.y - ay1[j]) / ha[j]) / 0.2f;
        rv.z = ((gt.z - ax2[j]) / wa[j]) / 0.2f;
        rv.w = ((gt.w - ay2[j]) / ha[j]) / 0.2f;
        *reinterpret_cast<float4*>(out + REG_OFF + ((size_t)b * An + a + j) * 4) = rv;
    }

    // cls one-hot: stage labels (-1 if not positive), then block-cooperative
    // fully-coalesced float4 writes of the ABLK*80-float region.
    __shared__ int slab[ABLK];
    #pragma unroll
    for (int j = 0; j < APT; ++j)
        slab[tid * APT + j] = (st[j] == 1.0f) ? (int)slabel[besti[j]] : -1;
    __syncthreads();

    float4* dst = reinterpret_cast<float4*>(out + CLS_OFF + ((size_t)b * An + a0) * NUM_CLASSES);
    #pragma unroll
    for (int i = 0; i < (ABLK * 20) / TB; ++i) {   // 40 float4s per thread
        const int p4  = tid + i * TB;              // 0..10239
        const int anc = p4 / 20;                   // 20 float4 per anchor
        const int c0  = (p4 - anc * 20) * 4;
        const int lab = slab[anc];
        float4 v;
        v.x = (c0     == lab) ? 1.0f : 0.0f;
        v.y = (c0 + 1 == lab) ? 1.0f : 0.0f;
        v.z = (c0 + 2 == lab) ? 1.0f : 0.0f;
        v.w = (c0 + 3 == lab) ? 1.0f : 0.0f;
        dst[p4] = v;
    }
}

extern "C" void kernel_launch(void* const* d_in, const int* in_sizes, int n_in,
                              void* d_out, int out_size, void* d_ws, size_t ws_size,
                              hipStream_t stream) {
    const float* ann     = (const float*)d_in[0];   // (8,128,5)
    const float* anchors = (const float*)d_in[1];   // (131072,4)
    float* out = (float*)d_out;

    dim3 grid(An / ABLK, Bn, 1);   // 256 x 8 = 2048 blocks
    dim3 block(TB, 1, 1);
    targets_kernel<<<grid, block, 0, stream>>>(ann, anchors, out);
}